// Round 7
// baseline (325.485 us; speedup 1.0000x reference)
//
#include <hip/hip_runtime.h>
#include <hip/hip_bf16.h>

// LinearAttention_MLP on MI355X — round 7.
// Math: k-softmax over size-1 axis == 1 -> s = 0.125 exactly -> out = 0.125*v.
// Fold: y = x @ Weff^T, Weff = 0.125*Wo@Wv (1024x1024).
// Measured facts driving this round:
//   - wall = Sum(kernel durs) + ~92-96us fixed overhead (launch-count independent)
//   - r3 all-bf16 async GEMM = 51us; fusing fp32 cast into its K-loop regressed
//     (r5: 72us reg-prefetch vmcnt stall; r6: 85us ds_read+cvt ahead of MFMA)
// Pipeline (memset + 2 launches):
//   prep      : blocks 0..255 weff GEMM  ||  blocks 256..8447 cast x->bf16
//               (BW-bound cast overlaps latency-bound weff)
//   gemm_norm : r3-structure bf16 GEMM writes y_bf; per-m-strip atomic counter;
//               8th-arriver block normalizes the strip's 128 rows (L2-hot y).

typedef __attribute__((ext_vector_type(8))) short bf16x8;
typedef __attribute__((ext_vector_type(4))) float f32x4;

struct alignas(16) bfvec8 { __hip_bfloat16 h[8]; };

__device__ __forceinline__ bfvec8 pack8(float4 a, float4 b) {
    bfvec8 o;
    o.h[0] = __float2bfloat16(a.x); o.h[1] = __float2bfloat16(a.y);
    o.h[2] = __float2bfloat16(a.z); o.h[3] = __float2bfloat16(a.w);
    o.h[4] = __float2bfloat16(b.x); o.h[5] = __float2bfloat16(b.y);
    o.h[6] = __float2bfloat16(b.z); o.h[7] = __float2bfloat16(b.w);
    return o;
}

// ---------------- prep: blocks 0..255 = weff 64x64 tile; 256.. = cast x ----------------
// weff: Weff = 0.125 * Wo @ Wv. Wo (1024,512) row-major; Wv (512,1024) transposed in LDS.
__global__ __launch_bounds__(256)
void prep(const float* __restrict__ Wo, const float* __restrict__ Wv,
          __hip_bfloat16* __restrict__ Weff,
          const float* __restrict__ x, bfvec8* __restrict__ x_bf) {
    const int tid = threadIdx.x;

    if (blockIdx.x >= 256) {   // ---- cast path: 8192 blocks x 256 slots of 8 floats
        int i = (blockIdx.x - 256) * 256 + tid;
        const float4* p = (const float4*)x + (size_t)i * 2;
        x_bf[i] = pack8(p[0], p[1]);
        return;
    }

    // ---- weff path (validated round 5/6) ----
    __shared__ __align__(16) __hip_bfloat16 As[64 * 32];
    __shared__ __align__(16) __hip_bfloat16 Bs[64 * 32];
    __shared__ __align__(16) float Bf[32 * 65];

    const int lane = tid & 63;
    const int wave = tid >> 6;
    const int wm   = wave >> 1;
    const int wn   = wave & 1;
    const int quad = lane >> 4;
    const int tr   = lane & 15;
    const int m0   = (blockIdx.x >> 4) * 64;
    const int n0   = (blockIdx.x & 15) * 64;

    f32x4 acc[2][2];
#pragma unroll
    for (int i = 0; i < 2; ++i)
#pragma unroll
        for (int j = 0; j < 2; ++j)
            acc[i][j] = (f32x4){0.f, 0.f, 0.f, 0.f};

    for (int kt = 0; kt < 512; kt += 32) {
        {   // A: LDS chunk c holds global chunk c ^ s
            int r = tid >> 2, c = tid & 3;
            int s = (r >> 1) & 3;
            int kg = (c ^ s) << 3;
            const float* sp = Wo + (size_t)(m0 + r) * 512 + kt + kg;
            float4 a = *(const float4*)sp, b = *(const float4*)(sp + 4);
            *(bfvec8*)(As + r * 32 + (c << 3)) = pack8(a, b);
        }
        {   // B fp32 rows (coalesced) -> Bf
            int kr = tid >> 3, c8 = (tid & 7) << 3;
            const float* sp = Wv + (size_t)(kt + kr) * 1024 + n0 + c8;
            float4 a = *(const float4*)sp, b = *(const float4*)(sp + 4);
            *(float4*)(Bf + kr * 65 + c8)     = a;
            *(float4*)(Bf + kr * 65 + c8 + 4) = b;
        }
        __syncthreads();
        {   // transpose + cvt: LDS chunk (cc ^ s) holds global chunk cc
            int n = tid >> 2, cc = tid & 3, k8 = cc << 3;
            float4 a, b;
            a.x = Bf[(k8 + 0) * 65 + n]; a.y = Bf[(k8 + 1) * 65 + n];
            a.z = Bf[(k8 + 2) * 65 + n]; a.w = Bf[(k8 + 3) * 65 + n];
            b.x = Bf[(k8 + 4) * 65 + n]; b.y = Bf[(k8 + 5) * 65 + n];
            b.z = Bf[(k8 + 6) * 65 + n]; b.w = Bf[(k8 + 7) * 65 + n];
            int cs = cc ^ ((n >> 1) & 3);
            *(bfvec8*)(Bs + n * 32 + cs * 8) = pack8(a, b);
        }
        __syncthreads();

        bf16x8 af[2], bf[2];
#pragma unroll
        for (int mi = 0; mi < 2; ++mi) {
            int r = wm * 32 + mi * 16 + tr;
            int c = quad ^ ((r >> 1) & 3);
            af[mi] = *(const bf16x8*)(As + r * 32 + c * 8);
        }
#pragma unroll
        for (int ni = 0; ni < 2; ++ni) {
            int r = wn * 32 + ni * 16 + tr;
            int c = quad ^ ((r >> 1) & 3);
            bf[ni] = *(const bf16x8*)(Bs + r * 32 + c * 8);
        }
#pragma unroll
        for (int mi = 0; mi < 2; ++mi)
#pragma unroll
            for (int ni = 0; ni < 2; ++ni)
                acc[mi][ni] = __builtin_amdgcn_mfma_f32_16x16x32_bf16(
                    af[mi], bf[ni], acc[mi][ni], 0, 0, 0);
        __syncthreads();
    }

#pragma unroll
    for (int mi = 0; mi < 2; ++mi)
#pragma unroll
        for (int ni = 0; ni < 2; ++ni) {
            const int col = n0 + wn * 32 + ni * 16 + tr;
#pragma unroll
            for (int r = 0; r < 4; ++r) {
                const int row = m0 + wm * 32 + mi * 16 + quad * 4 + r;
                Weff[(size_t)row * 1024 + col] =
                    __float2bfloat16(acc[mi][ni][r] * 0.125f);
            }
        }
}

// ---------------- gemm_norm: y = x@Weff^T + b (bf16), then last-arriver row norm ----------------
// M=16384, N=1024, K=1024, BLK=128, BK=64. 1024 blocks (r3 structure: 51us measured).
// After the y-tile store, the 8th block of each 128-row m-strip normalizes the strip.
__global__ __launch_bounds__(256)
void gemm_norm(const __hip_bfloat16* __restrict__ A,
               const __hip_bfloat16* __restrict__ Bt,
               const float* __restrict__ bias,
               const float* __restrict__ g,
               __hip_bfloat16* __restrict__ Y,
               float* __restrict__ out,
               unsigned int* __restrict__ counters) {
    __shared__ __align__(16) __hip_bfloat16 As[128 * 64];
    __shared__ __align__(16) __hip_bfloat16 Bs[128 * 64];

    const int tid  = threadIdx.x;
    const int lane = tid & 63;
    const int wave = tid >> 6;
    const int wm   = wave >> 1;
    const int wn   = wave & 1;
    const int quad = lane >> 4;
    const int tr   = lane & 15;

    // XCD-aware mapping: all 8 n-tiles of an m-strip on one XCD (A fetched once).
    const int b   = blockIdx.x;
    const int xcd = b & 7;
    const int t   = b >> 3;
    const int nt  = t & 7;
    const int mt  = (t >> 3) * 8 + xcd;
    const int m0  = mt * 128;
    const int n0  = nt * 128;

    f32x4 acc[4][4];
#pragma unroll
    for (int i = 0; i < 4; ++i)
#pragma unroll
        for (int j = 0; j < 4; ++j)
            acc[i][j] = (f32x4){0.f, 0.f, 0.f, 0.f};

    // Staging slots: LDS chunk c (=L&7) holds global chunk c ^ (r&7).
    int rr[4], kgg[4];
#pragma unroll
    for (int i = 0; i < 4; ++i) {
        int L = i * 256 + tid;
        rr[i]  = L >> 3;
        int c  = L & 7;
        kgg[i] = (c ^ (rr[i] & 7)) << 3;
    }

    for (int kt = 0; kt < 1024; kt += 64) {
#pragma unroll
        for (int i = 0; i < 4; ++i) {
            int L = i * 256 + tid;
            const __hip_bfloat16* ga = A  + (size_t)(m0 + rr[i]) * 1024 + kt + kgg[i];
            const __hip_bfloat16* gb = Bt + (size_t)(n0 + rr[i]) * 1024 + kt + kgg[i];
            __builtin_amdgcn_global_load_lds(
                (const __attribute__((address_space(1))) void*)ga,
                (__attribute__((address_space(3))) void*)(As + (size_t)L * 8), 16, 0, 0);
            __builtin_amdgcn_global_load_lds(
                (const __attribute__((address_space(1))) void*)gb,
                (__attribute__((address_space(3))) void*)(Bs + (size_t)L * 8), 16, 0, 0);
        }
        __syncthreads();

#pragma unroll
        for (int ko = 0; ko < 2; ++ko) {
            bf16x8 af[4], bf[4];
#pragma unroll
            for (int mi = 0; mi < 4; ++mi) {
                int r = wm * 64 + mi * 16 + tr;
                int c = (ko * 4 + quad) ^ (r & 7);
                af[mi] = *(const bf16x8*)(As + (r * 8 + c) * 8);
            }
#pragma unroll
            for (int ni = 0; ni < 4; ++ni) {
                int r = wn * 64 + ni * 16 + tr;
                int c = (ko * 4 + quad) ^ (r & 7);
                bf[ni] = *(const bf16x8*)(Bs + (r * 8 + c) * 8);
            }
#pragma unroll
            for (int mi = 0; mi < 4; ++mi)
#pragma unroll
                for (int ni = 0; ni < 4; ++ni)
                    acc[mi][ni] = __builtin_amdgcn_mfma_f32_16x16x32_bf16(
                        af[mi], bf[ni], acc[mi][ni], 0, 0, 0);
        }
        __syncthreads();
    }

    // Epilogue: write y tile. C/D layout: col = lane&15, row = quad*4 + reg.
#pragma unroll
    for (int mi = 0; mi < 4; ++mi)
#pragma unroll
        for (int ni = 0; ni < 4; ++ni) {
            const int col = n0 + wn * 64 + ni * 16 + tr;
            const float bv = bias[col];
#pragma unroll
            for (int r = 0; r < 4; ++r) {
                const int row = m0 + wm * 64 + mi * 16 + quad * 4 + r;
                Y[(size_t)row * 1024 + col] = __float2bfloat16(acc[mi][ni][r] + bv);
            }
        }

    // ---- strip-completion handshake ----
    __syncthreads();   // per-wave vmcnt(0) drain before barrier: all y stores complete
    __shared__ int is_last;
    if (tid == 0) {
        __threadfence();                               // release (L2 writeback, agent scope)
        unsigned int old = atomicAdd(&counters[mt], 1u);  // device-scope by default
        is_last = (old == 7u);
    }
    __syncthreads();
    if (!is_last) return;
    __threadfence();                                   // acquire (invalidate stale caches)

    // ---- norm phase: this block normalizes rows m0..m0+127 ----
    // wave w handles row (m0 + it*4 + w); lane covers 16 cols. No LDS needed.
    float4 g0 = *(const float4*)(g + lane * 16);
    float4 g1 = *(const float4*)(g + lane * 16 + 4);
    float4 g2 = *(const float4*)(g + lane * 16 + 8);
    float4 g3 = *(const float4*)(g + lane * 16 + 12);

    for (int it = 0; it < 32; ++it) {
        const int row = m0 + it * 4 + wave;
        const ushort* yp = (const ushort*)Y + (size_t)row * 1024 + lane * 16;
        union { uint4 u; ushort s[8]; } U0, U1;
        U0.u = *(const uint4*)yp;
        U1.u = *(const uint4*)(yp + 8);
        float v[16];
#pragma unroll
        for (int j = 0; j < 8; ++j) v[j]     = __bfloat162float(*(const __hip_bfloat16*)&U0.s[j]);
#pragma unroll
        for (int j = 0; j < 8; ++j) v[8 + j] = __bfloat162float(*(const __hip_bfloat16*)&U1.s[j]);

        float ss = 0.f;
#pragma unroll
        for (int j = 0; j < 16; ++j) ss += v[j] * v[j];
#pragma unroll
        for (int off = 1; off < 64; off <<= 1)
            ss += __shfl_xor(ss, off, 64);             // butterfly: all lanes get total
        const float sc = 32.0f / fmaxf(sqrtf(ss), 1e-12f);

        float* op = out + (size_t)row * 1024 + lane * 16;
        float4 o;
        o.x = v[0]  * sc * g0.x; o.y = v[1]  * sc * g0.y; o.z = v[2]  * sc * g0.z; o.w = v[3]  * sc * g0.w;
        *(float4*)(op)      = o;
        o.x = v[4]  * sc * g1.x; o.y = v[5]  * sc * g1.y; o.z = v[6]  * sc * g1.z; o.w = v[7]  * sc * g1.w;
        *(float4*)(op + 4)  = o;
        o.x = v[8]  * sc * g2.x; o.y = v[9]  * sc * g2.y; o.z = v[10] * sc * g2.z; o.w = v[11] * sc * g2.w;
        *(float4*)(op + 8)  = o;
        o.x = v[12] * sc * g3.x; o.y = v[13] * sc * g3.y; o.z = v[14] * sc * g3.z; o.w = v[15] * sc * g3.w;
        *(float4*)(op + 12) = o;
    }
}

extern "C" void kernel_launch(void* const* d_in, const int* in_sizes, int n_in,
                              void* d_out, int out_size, void* d_ws, size_t ws_size,
                              hipStream_t stream) {
    const float* x     = (const float*)d_in[0];   // (16384, 1024)
    const float* w_qkv = (const float*)d_in[1];   // (1536, 1024)
    const float* w_out = (const float*)d_in[2];   // (1024, 512)
    const float* b_out = (const float*)d_in[3];   // (1024,)
    const float* g     = (const float*)d_in[4];   // (1, 1024)

    const int B = 16384, D = 1024, H = 512;
    const float* wv = w_qkv + (size_t)2 * H * D;  // v-rows: (512, 1024)

    char* ws = (char*)d_ws;
    size_t off = 0;
    __hip_bfloat16* x_bf    = (__hip_bfloat16*)(ws + off); off += (size_t)B * D * 2;  // 32 MB
    __hip_bfloat16* weff_bf = (__hip_bfloat16*)(ws + off); off += (size_t)D * D * 2;  // 2 MB
    __hip_bfloat16* y_bf    = (__hip_bfloat16*)(ws + off); off += (size_t)B * D * 2;  // 32 MB
    unsigned int*   counters = (unsigned int*)(ws + off);  off += 128 * sizeof(unsigned int);

    hipMemsetAsync(counters, 0, 128 * sizeof(unsigned int), stream);
    prep<<<256 + (B * D / 8) / 256, 256, 0, stream>>>(w_out, wv, weff_bf, x, (bfvec8*)x_bf);
    gemm_norm<<<1024, 256, 0, stream>>>(x_bf, weff_bf, b_out, g, y_bf, (float*)d_out, counters);
}